// Round 1
// baseline (435.703 us; speedup 1.0000x reference)
//
#include <hip/hip_runtime.h>
#include <hip/hip_bf16.h>
#include <cstdint>

#define EMB 1024
#define HEADS 16
#define HD 64
#define BATCH 4
#define SEQ 2048
#define BT (BATCH*SEQ)                 // 8192 tokens
#define LNEPS 1e-5f
#define QK_SCALE 0.17677669529663687f  // 1024^-0.25

typedef __bf16 bf16;
typedef __bf16 bf16x8 __attribute__((ext_vector_type(8)));
typedef __bf16 bf16x4 __attribute__((ext_vector_type(4)));
typedef float  f32x4  __attribute__((ext_vector_type(4)));

typedef const __attribute__((address_space(1))) void* gas_ptr;
typedef __attribute__((address_space(3))) void*       las_ptr;

__device__ __forceinline__ void gld_lds16(const void* g, void* l) {
  __builtin_amdgcn_global_load_lds((gas_ptr)g, (las_ptr)l, 16, 0, 0);
}

// ---------------- fp32 -> bf16 conversion ----------------
__global__ void cvt_f32_bf16(const float* __restrict__ src, bf16* __restrict__ dst, int n4) {
  int i = blockIdx.x * blockDim.x + threadIdx.x;
  if (i >= n4) return;
  float4 f = reinterpret_cast<const float4*>(src)[i];
  bf16x4 o = { (bf16)f.x, (bf16)f.y, (bf16)f.z, (bf16)f.w };
  reinterpret_cast<bf16x4*>(dst)[i] = o;
}

// 4 weight matrices (1024x1024 each) -> contiguous bf16 [4*1024][1024]
__global__ void cvt_w4(const float* __restrict__ w0, const float* __restrict__ w1,
                       const float* __restrict__ w2, const float* __restrict__ w3,
                       bf16* __restrict__ dst) {
  int i = blockIdx.x * blockDim.x + threadIdx.x;   // over 4*262144 float4s
  int sel = i >> 18;
  int j = i & 262143;
  const float* s = (sel == 0) ? w0 : (sel == 1) ? w1 : (sel == 2) ? w2 : w3;
  float4 f = reinterpret_cast<const float4*>(s)[j];
  bf16x4 o = { (bf16)f.x, (bf16)f.y, (bf16)f.z, (bf16)f.w };
  reinterpret_cast<bf16x4*>(dst)[i] = o;
}

// ---------------- m97-style GEMM: C[M][N] = A[M][K] * B[N][K]^T ----------------
// A row-major [M][K], B row-major [N][K] (i.e. torch Linear weight layout).
// OUTF32=0: write bf16 C. OUTF32=1: write fp32 C + bias[col].
template<int OUTF32>
__global__ __launch_bounds__(256, 2) void gemm_bt(
    const bf16* __restrict__ A, const bf16* __restrict__ Bm,
    bf16* __restrict__ Cb, float* __restrict__ Cf, const float* __restrict__ bias,
    int M, int N, int K)
{
  __shared__ __align__(16) bf16 As[128 * 32];
  __shared__ __align__(16) bf16 Bs[128 * 32];

  const int t    = threadIdx.x;
  const int lane = t & 63;
  const int wave = t >> 6;
  const int q    = lane >> 4;
  const int ln   = lane & 15;
  const int m0   = blockIdx.y * 128;
  const int n0   = blockIdx.x * 128;
  const int wm   = (wave >> 1) * 64;
  const int wn   = (wave & 1) * 64;

  const int r0 = t >> 2;          // staging row within tile (0..63)
  const int c0 = (t & 3) << 3;    // staging col (0,8,16,24)

  f32x4 zero4 = {0.f, 0.f, 0.f, 0.f};
  f32x4 acc[4][4];
#pragma unroll
  for (int i = 0; i < 4; i++)
#pragma unroll
    for (int j = 0; j < 4; j++) acc[i][j] = zero4;

  for (int k0 = 0; k0 < K; k0 += 32) {
    __syncthreads();
    const bf16* ga = A  + (size_t)(m0 + r0) * K + k0 + c0;
    const bf16* gb = Bm + (size_t)(n0 + r0) * K + k0 + c0;
    gld_lds16(ga,                  &As[t * 8]);
    gld_lds16(ga + (size_t)64 * K, &As[t * 8 + 2048]);
    gld_lds16(gb,                  &Bs[t * 8]);
    gld_lds16(gb + (size_t)64 * K, &Bs[t * 8 + 2048]);
    __syncthreads();

    bf16x8 af[4], bfr[4];
#pragma unroll
    for (int mi = 0; mi < 4; mi++)
      af[mi] = *reinterpret_cast<const bf16x8*>(&As[(wm + mi * 16 + ln) * 32 + q * 8]);
#pragma unroll
    for (int ni = 0; ni < 4; ni++)
      bfr[ni] = *reinterpret_cast<const bf16x8*>(&Bs[(wn + ni * 16 + ln) * 32 + q * 8]);
#pragma unroll
    for (int mi = 0; mi < 4; mi++)
#pragma unroll
      for (int ni = 0; ni < 4; ni++)
        acc[mi][ni] = __builtin_amdgcn_mfma_f32_16x16x32_bf16(af[mi], bfr[ni], acc[mi][ni], 0, 0, 0);
  }

#pragma unroll
  for (int mi = 0; mi < 4; mi++) {
#pragma unroll
    for (int ni = 0; ni < 4; ni++) {
#pragma unroll
      for (int r = 0; r < 4; r++) {
        int row = m0 + wm + mi * 16 + q * 4 + r;
        int col = n0 + wn + ni * 16 + ln;
        float v = acc[mi][ni][r];
        if (OUTF32) Cf[(size_t)row * N + col] = v + bias[col];
        else        Cb[(size_t)row * N + col] = (bf16)v;
      }
    }
  }
}

// ---------------- per-head LayerNorm (+scale) with rearrange to [bh][t][64] ----------------
// in: bf16, row stride ldin, token t row = t*ldin (+ caller-applied col offset).
__global__ void ln_head(const bf16* __restrict__ in, int ldin, bf16* __restrict__ out,
                        const float* __restrict__ g, const float* __restrict__ bvec, float scale)
{
  int wave = threadIdx.x >> 6, lane = threadIdx.x & 63;
  int row = blockIdx.x * 4 + wave;        // row = t*16 + h,  t in [0,8192)
  int tok = row >> 4, h = row & 15;
  float x = (float)in[(size_t)tok * ldin + h * HD + lane];
  float s = x;
#pragma unroll
  for (int m = 1; m < 64; m <<= 1) s += __shfl_xor(s, m, 64);
  float mean = s * (1.f / 64.f);
  float d = x - mean;
  float vs = d * d;
#pragma unroll
  for (int m = 1; m < 64; m <<= 1) vs += __shfl_xor(vs, m, 64);
  float var = vs * (1.f / 64.f);
  float y = (d * rsqrtf(var + LNEPS) * g[lane] + bvec[lane]) * scale;
  int b = tok >> 11;            // /2048
  int tt = tok & 2047;
  int bh = b * HEADS + h;
  out[((size_t)bh * SEQ + tt) * HD + lane] = (bf16)y;
}

// ---------------- V transpose: [t][E] (col offset applied) -> [bh][64 d][2048 t] ----------------
__global__ void v_trans(const bf16* __restrict__ in, int ldin, bf16* __restrict__ out)
{
  __shared__ __align__(16) bf16 tile[64][72];
  int bh = blockIdx.y, jt = blockIdx.x;
  int b = bh >> 4, h = bh & 15;
  int t = threadIdx.x;
#pragma unroll
  for (int p = 0; p < 2; p++) {
    int rowj = p * 32 + (t >> 3);
    int cold = (t & 7) << 3;
    bf16x8 v = *reinterpret_cast<const bf16x8*>(
        &in[(size_t)(b * SEQ + jt * 64 + rowj) * ldin + h * HD + cold]);
    *reinterpret_cast<bf16x8*>(&tile[rowj][cold]) = v;
  }
  __syncthreads();
#pragma unroll
  for (int p = 0; p < 2; p++) {
    int rowd = p * 32 + (t >> 3);
    int colj = (t & 7) << 3;
    bf16x8 v;
#pragma unroll
    for (int jj = 0; jj < 8; jj++) v[jj] = tile[colj + jj][rowd];
    *reinterpret_cast<bf16x8*>(&out[((size_t)bh * HD + rowd) * SEQ + jt * 64 + colj]) = v;
  }
}

// ---------------- flash attention (causal) ----------------
// Qn,Kn: [bh][t][64] bf16 (already LN'd and scaled). Vt: [bh][64][2048].
// O: [b*T + t][EMB] bf16.
__global__ __launch_bounds__(256, 2) void attn(
    const bf16* __restrict__ Qn, const bf16* __restrict__ Kn, const bf16* __restrict__ Vt,
    bf16* __restrict__ O)
{
  __shared__ __align__(16) bf16 Ks[64 * 64];
  __shared__ __align__(16) bf16 Vs[64 * 64];
  __shared__ __align__(16) bf16 Ps[4][16 * 72];

  const int bh = blockIdx.y;
  const int i0 = blockIdx.x * 64;
  const int t = threadIdx.x, wave = t >> 6, lane = t & 63;
  const int q = lane >> 4, ln = lane & 15;

  // Q fragments (A operand), held in registers for the whole block
  const bf16* qb = Qn + ((size_t)bh * SEQ + i0 + wave * 16 + ln) * HD + q * 8;
  bf16x8 qf0 = *reinterpret_cast<const bf16x8*>(qb);
  bf16x8 qf1 = *reinterpret_cast<const bf16x8*>(qb + 32);

  float mrow[4], lrow[4];
  f32x4 zero4 = {0.f, 0.f, 0.f, 0.f};
  f32x4 oacc[4];
#pragma unroll
  for (int r = 0; r < 4; r++) { mrow[r] = -3.0e38f; lrow[r] = 0.f; }
#pragma unroll
  for (int ni = 0; ni < 4; ni++) oacc[ni] = zero4;

  const int nj = (i0 >> 6) + 1;
  for (int jt = 0; jt < nj; jt++) {
    const int j0 = jt * 64;
    __syncthreads();
    // stage K (rows j, 64 d) and V^T (rows d, 64 j) with 16B-chunk XOR swizzle
#pragma unroll
    for (int s = 0; s < 2; s++) {
      int u = t * 8 + s * 2048;
      int row = u >> 6, cs = (u >> 3) & 7;
      int csrc = cs ^ (row & 7);
      gld_lds16(Kn + ((size_t)bh * SEQ + j0 + row) * HD + csrc * 8, &Ks[u]);
      gld_lds16(Vt + ((size_t)bh * HD + row) * SEQ + j0 + csrc * 8, &Vs[u]);
    }
    __syncthreads();

    // S = Q K^T  (per wave: 16 rows x 64 cols)
    f32x4 s4[4];
#pragma unroll
    for (int ni = 0; ni < 4; ni++) {
      int rowj = ni * 16 + ln;
      bf16x8 kf0 = *reinterpret_cast<const bf16x8*>(&Ks[rowj * 64 + ((0 * 4 + q) ^ (rowj & 7)) * 8]);
      bf16x8 kf1 = *reinterpret_cast<const bf16x8*>(&Ks[rowj * 64 + ((1 * 4 + q) ^ (rowj & 7)) * 8]);
      f32x4 z = zero4;
      z = __builtin_amdgcn_mfma_f32_16x16x32_bf16(qf0, kf0, z, 0, 0, 0);
      z = __builtin_amdgcn_mfma_f32_16x16x32_bf16(qf1, kf1, z, 0, 0, 0);
      s4[ni] = z;
    }

    // causal mask (only the diagonal tile is partial)
    if (j0 == i0) {
#pragma unroll
      for (int ni = 0; ni < 4; ni++)
#pragma unroll
        for (int r = 0; r < 4; r++) {
          int irow = i0 + wave * 16 + q * 4 + r;
          int jcol = j0 + ni * 16 + ln;
          if (jcol > irow) s4[ni][r] = -3.0e38f;
        }
    }

    // online softmax: rows live in 16-lane groups (fixed q), 4 rows per lane
#pragma unroll
    for (int r = 0; r < 4; r++) {
      float mx = fmaxf(fmaxf(s4[0][r], s4[1][r]), fmaxf(s4[2][r], s4[3][r]));
#pragma unroll
      for (int mk = 1; mk < 16; mk <<= 1) mx = fmaxf(mx, __shfl_xor(mx, mk, 64));
      float mnew = fmaxf(mrow[r], mx);
      float al = __expf(mrow[r] - mnew);
      mrow[r] = mnew;
      float ps = 0.f;
#pragma unroll
      for (int ni = 0; ni < 4; ni++) {
        float p = __expf(s4[ni][r] - mnew);
        s4[ni][r] = p;
        ps += p;
      }
#pragma unroll
      for (int mk = 1; mk < 16; mk <<= 1) ps += __shfl_xor(ps, mk, 64);
      lrow[r] = lrow[r] * al + ps;
#pragma unroll
      for (int ni = 0; ni < 4; ni++) oacc[ni][r] *= al;
    }

    // P: C-layout -> LDS -> A-layout (per-wave scratch, padded rows)
#pragma unroll
    for (int ni = 0; ni < 4; ni++)
#pragma unroll
      for (int r = 0; r < 4; r++)
        Ps[wave][(q * 4 + r) * 72 + ni * 16 + ln] = (bf16)s4[ni][r];
    asm volatile("s_waitcnt lgkmcnt(0)" ::: "memory");

    bf16x8 pf0 = *reinterpret_cast<const bf16x8*>(&Ps[wave][ln * 72 + q * 8]);
    bf16x8 pf1 = *reinterpret_cast<const bf16x8*>(&Ps[wave][ln * 72 + 32 + q * 8]);
#pragma unroll
    for (int ni = 0; ni < 4; ni++) {
      int rowd = ni * 16 + ln;
      bf16x8 vf0 = *reinterpret_cast<const bf16x8*>(&Vs[rowd * 64 + ((0 * 4 + q) ^ (rowd & 7)) * 8]);
      bf16x8 vf1 = *reinterpret_cast<const bf16x8*>(&Vs[rowd * 64 + ((1 * 4 + q) ^ (rowd & 7)) * 8]);
      oacc[ni] = __builtin_amdgcn_mfma_f32_16x16x32_bf16(pf0, vf0, oacc[ni], 0, 0, 0);
      oacc[ni] = __builtin_amdgcn_mfma_f32_16x16x32_bf16(pf1, vf1, oacc[ni], 0, 0, 0);
    }
  }

  // epilogue: normalize and store to [b*T + t][EMB]
  float inv[4];
#pragma unroll
  for (int r = 0; r < 4; r++) inv[r] = 1.f / lrow[r];
  int b = bh >> 4, h = bh & 15;
#pragma unroll
  for (int ni = 0; ni < 4; ni++)
#pragma unroll
    for (int r = 0; r < 4; r++) {
      int row = i0 + wave * 16 + q * 4 + r;
      O[(size_t)(b * SEQ + row) * EMB + h * HD + ni * 16 + ln] = (bf16)(oacc[ni][r] * inv[r]);
    }
}

// ---------------- launch ----------------
extern "C" void kernel_launch(void* const* d_in, const int* in_sizes, int n_in,
                              void* d_out, int out_size, void* d_ws, size_t ws_size,
                              hipStream_t stream)
{
  const float* x   = (const float*)d_in[0];
  const float* Wk  = (const float*)d_in[1];
  const float* Wq  = (const float*)d_in[2];
  const float* Wv  = (const float*)d_in[3];
  const float* Wo  = (const float*)d_in[4];
  const float* bo  = (const float*)d_in[5];
  const float* klg = (const float*)d_in[6];
  const float* klb = (const float*)d_in[7];
  const float* qlg = (const float*)d_in[8];
  const float* qlb = (const float*)d_in[9];
  float* out = (float*)d_out;

  char* ws = (char*)d_ws;
  // workspace layout (bytes)
  const size_t OFF_XB  = 0;                               // bf16 x       [8192][1024]   16 MB
  const size_t OFF_WB  = OFF_XB  + (size_t)BT * EMB * 2;  // bf16 W kqvo  [4096][1024]    8 MB
  const size_t OFF_KQV = OFF_WB  + (size_t)4 * EMB * EMB * 2; // bf16 KQV [8192][3072]   48 MB
  const size_t OFF_KN  = OFF_KQV + (size_t)BT * 3 * EMB * 2;  // bf16 [64][2048][64]     16 MB
  const size_t OFF_QN  = OFF_KN  + (size_t)BT * EMB * 2;
  const size_t OFF_VT  = OFF_QN  + (size_t)BT * EMB * 2;
  const size_t OFF_END = OFF_VT  + (size_t)BT * EMB * 2;
  if (ws_size < OFF_END) return;  // workspace too small -> fail loudly via validation

  bf16* xb   = (bf16*)(ws + OFF_XB);
  bf16* wb   = (bf16*)(ws + OFF_WB);     // Wk|Wq|Wv|Wo stacked rows
  bf16* kqv  = (bf16*)(ws + OFF_KQV);
  bf16* kn   = (bf16*)(ws + OFF_KN);
  bf16* qn   = (bf16*)(ws + OFF_QN);
  bf16* vt   = (bf16*)(ws + OFF_VT);
  bf16* ob   = (bf16*)(ws + OFF_KQV);    // alias: KQV dead after ln/v_trans

  // 1) fp32 -> bf16
  cvt_f32_bf16<<<(BT * EMB / 4) / 256, 256, 0, stream>>>(x, xb, BT * EMB / 4);
  cvt_w4<<<(4 * EMB * EMB / 4) / 256, 256, 0, stream>>>(Wk, Wq, Wv, Wo, wb);

  // 2) fused K|Q|V projection GEMM: [8192][3072] = xb [8192][1024] * Wkqv[3072][1024]^T
  gemm_bt<0><<<dim3(3 * EMB / 128, BT / 128), 256, 0, stream>>>(
      xb, wb, kqv, (float*)nullptr, (const float*)nullptr, BT, 3 * EMB, EMB);

  // 3) per-head LN + scale + rearrange; V transpose
  ln_head<<<BT * HEADS / 4, 256, 0, stream>>>(kqv + 0 * EMB, 3 * EMB, kn, klg, klb, QK_SCALE);
  ln_head<<<BT * HEADS / 4, 256, 0, stream>>>(kqv + 1 * EMB, 3 * EMB, qn, qlg, qlb, QK_SCALE);
  v_trans<<<dim3(SEQ / 64, BATCH * HEADS), 256, 0, stream>>>(kqv + 2 * EMB, 3 * EMB, vt);

  // 4) causal flash attention -> ob [8192][1024]
  attn<<<dim3(SEQ / 64, BATCH * HEADS), 256, 0, stream>>>(qn, kn, vt, ob);

  // 5) output projection + bias -> fp32 d_out
  gemm_bt<1><<<dim3(EMB / 128, BT / 128), 256, 0, stream>>>(
      ob, wb + (size_t)3 * EMB * EMB, (bf16*)nullptr, out, bo, BT, EMB, EMB);
}

// Round 3
// 370.986 us; speedup vs baseline: 1.1744x; 1.1744x over previous
//
#include <hip/hip_runtime.h>
#include <hip/hip_bf16.h>
#include <cstdint>

#define EMB 1024
#define HEADS 16
#define HD 64
#define BATCH 4
#define SEQ 2048
#define BT (BATCH*SEQ)                 // 8192 tokens
#define LNEPS 1e-5f
#define QK_SCALE 0.17677669529663687f  // 1024^-0.25

typedef __bf16 bf16;
typedef __bf16 bf16x8 __attribute__((ext_vector_type(8)));
typedef __bf16 bf16x4 __attribute__((ext_vector_type(4)));
typedef float  f32x4  __attribute__((ext_vector_type(4)));

typedef const __attribute__((address_space(1))) void* gas_ptr;
typedef __attribute__((address_space(3))) void*       las_ptr;

__device__ __forceinline__ void gld_lds16(const void* g, void* l) {
  __builtin_amdgcn_global_load_lds((gas_ptr)g, (las_ptr)l, 16, 0, 0);
}

// ---------------- fp32 -> bf16 conversion ----------------
__global__ void cvt_f32_bf16(const float* __restrict__ src, bf16* __restrict__ dst, int n4) {
  int i = blockIdx.x * blockDim.x + threadIdx.x;
  if (i >= n4) return;
  float4 f = reinterpret_cast<const float4*>(src)[i];
  bf16x4 o = { (bf16)f.x, (bf16)f.y, (bf16)f.z, (bf16)f.w };
  reinterpret_cast<bf16x4*>(dst)[i] = o;
}

// 4 weight matrices (1024x1024 each) -> contiguous bf16 [4*1024][1024]
__global__ void cvt_w4(const float* __restrict__ w0, const float* __restrict__ w1,
                       const float* __restrict__ w2, const float* __restrict__ w3,
                       bf16* __restrict__ dst) {
  int i = blockIdx.x * blockDim.x + threadIdx.x;   // over 4*262144 float4s
  int sel = i >> 18;
  int j = i & 262143;
  const float* s = (sel == 0) ? w0 : (sel == 1) ? w1 : (sel == 2) ? w2 : w3;
  float4 f = reinterpret_cast<const float4*>(s)[j];
  bf16x4 o = { (bf16)f.x, (bf16)f.y, (bf16)f.z, (bf16)f.w };
  reinterpret_cast<bf16x4*>(dst)[i] = o;
}

// ---------------- m97-style GEMM: C[M][N] = A[M][K] * B[N][K]^T ----------------
template<int OUTF32>
__global__ __launch_bounds__(256, 2) void gemm_bt(
    const bf16* __restrict__ A, const bf16* __restrict__ Bm,
    bf16* __restrict__ Cb, float* __restrict__ Cf, const float* __restrict__ bias,
    int M, int N, int K)
{
  __shared__ __align__(16) bf16 As[128 * 32];
  __shared__ __align__(16) bf16 Bs[128 * 32];

  const int t    = threadIdx.x;
  const int lane = t & 63;
  const int wave = t >> 6;
  const int q    = lane >> 4;
  const int ln   = lane & 15;
  const int m0   = blockIdx.y * 128;
  const int n0   = blockIdx.x * 128;
  const int wm   = (wave >> 1) * 64;
  const int wn   = (wave & 1) * 64;

  const int r0 = t >> 2;
  const int c0 = (t & 3) << 3;

  f32x4 zero4 = {0.f, 0.f, 0.f, 0.f};
  f32x4 acc[4][4];
#pragma unroll
  for (int i = 0; i < 4; i++)
#pragma unroll
    for (int j = 0; j < 4; j++) acc[i][j] = zero4;

  for (int k0 = 0; k0 < K; k0 += 32) {
    __syncthreads();
    const bf16* ga = A  + (size_t)(m0 + r0) * K + k0 + c0;
    const bf16* gb = Bm + (size_t)(n0 + r0) * K + k0 + c0;
    gld_lds16(ga,                  &As[t * 8]);
    gld_lds16(ga + (size_t)64 * K, &As[t * 8 + 2048]);
    gld_lds16(gb,                  &Bs[t * 8]);
    gld_lds16(gb + (size_t)64 * K, &Bs[t * 8 + 2048]);
    __syncthreads();

    bf16x8 af[4], bfr[4];
#pragma unroll
    for (int mi = 0; mi < 4; mi++)
      af[mi] = *reinterpret_cast<const bf16x8*>(&As[(wm + mi * 16 + ln) * 32 + q * 8]);
#pragma unroll
    for (int ni = 0; ni < 4; ni++)
      bfr[ni] = *reinterpret_cast<const bf16x8*>(&Bs[(wn + ni * 16 + ln) * 32 + q * 8]);
#pragma unroll
    for (int mi = 0; mi < 4; mi++)
#pragma unroll
      for (int ni = 0; ni < 4; ni++)
        acc[mi][ni] = __builtin_amdgcn_mfma_f32_16x16x32_bf16(af[mi], bfr[ni], acc[mi][ni], 0, 0, 0);
  }

#pragma unroll
  for (int mi = 0; mi < 4; mi++) {
#pragma unroll
    for (int ni = 0; ni < 4; ni++) {
#pragma unroll
      for (int r = 0; r < 4; r++) {
        int row = m0 + wm + mi * 16 + q * 4 + r;
        int col = n0 + wn + ni * 16 + ln;
        float v = acc[mi][ni][r];
        if (OUTF32) Cf[(size_t)row * N + col] = v + bias[col];
        else        Cb[(size_t)row * N + col] = (bf16)v;
      }
    }
  }
}

// ---------------- per-head LayerNorm (+scale) with rearrange to [bh][t][64] ----------------
__global__ void ln_head(const bf16* __restrict__ in, int ldin, bf16* __restrict__ out,
                        const float* __restrict__ g, const float* __restrict__ bvec, float scale)
{
  int wave = threadIdx.x >> 6, lane = threadIdx.x & 63;
  int row = blockIdx.x * 4 + wave;        // row = t*16 + h,  t in [0,8192)
  int tok = row >> 4, h = row & 15;
  float x = (float)in[(size_t)tok * ldin + h * HD + lane];
  float s = x;
#pragma unroll
  for (int m = 1; m < 64; m <<= 1) s += __shfl_xor(s, m, 64);
  float mean = s * (1.f / 64.f);
  float d = x - mean;
  float vs = d * d;
#pragma unroll
  for (int m = 1; m < 64; m <<= 1) vs += __shfl_xor(vs, m, 64);
  float var = vs * (1.f / 64.f);
  float y = (d * rsqrtf(var + LNEPS) * g[lane] + bvec[lane]) * scale;
  int b = tok >> 11;            // /2048
  int tt = tok & 2047;
  int bh = b * HEADS + h;
  out[((size_t)bh * SEQ + tt) * HD + lane] = (bf16)y;
}

// ---------------- V transpose: [t][E] -> [bh][64 d][2048 t] ----------------
__global__ void v_trans(const bf16* __restrict__ in, int ldin, bf16* __restrict__ out)
{
  __shared__ __align__(16) bf16 tile[64][72];
  int bh = blockIdx.y, jt = blockIdx.x;
  int b = bh >> 4, h = bh & 15;
  int t = threadIdx.x;
#pragma unroll
  for (int p = 0; p < 2; p++) {
    int rowj = p * 32 + (t >> 3);
    int cold = (t & 7) << 3;
    bf16x8 v = *reinterpret_cast<const bf16x8*>(
        &in[(size_t)(b * SEQ + jt * 64 + rowj) * ldin + h * HD + cold]);
    *reinterpret_cast<bf16x8*>(&tile[rowj][cold]) = v;
  }
  __syncthreads();
#pragma unroll
  for (int p = 0; p < 2; p++) {
    int rowd = p * 32 + (t >> 3);
    int colj = (t & 7) << 3;
    bf16x8 v;
#pragma unroll
    for (int jj = 0; jj < 8; jj++) v[jj] = tile[colj + jj][rowd];
    *reinterpret_cast<bf16x8*>(&out[((size_t)bh * HD + rowd) * SEQ + jt * 64 + colj]) = v;
  }
}

// ---------------- flash attention (causal), fixed-max softmax, dbuf staging ----------------
// Qn,Kn: [bh][t][64] bf16 (LN'd and scaled; |s| <= 2 guaranteed). Vt: [bh][64][2048].
__global__ __launch_bounds__(256, 3) void attn(
    const bf16* __restrict__ Qn, const bf16* __restrict__ Kn, const bf16* __restrict__ Vt,
    bf16* __restrict__ O)
{
  __shared__ __align__(16) bf16 Ks[2][64 * 64];
  __shared__ __align__(16) bf16 Vs[2][64 * 64];
  __shared__ __align__(16) bf16 Ps[4][16 * 72];

  const int bh = blockIdx.y;
  const int i0 = (gridDim.x - 1 - blockIdx.x) * 64;   // LPT: biggest blocks first
  const int t = threadIdx.x, wave = t >> 6, lane = t & 63;
  const int q = lane >> 4, ln = lane & 15;

  // Q fragments (A operand), registers for whole block
  const bf16* qb = Qn + ((size_t)bh * SEQ + i0 + wave * 16 + ln) * HD + q * 8;
  bf16x8 qf0 = *reinterpret_cast<const bf16x8*>(qb);
  bf16x8 qf1 = *reinterpret_cast<const bf16x8*>(qb + 32);

  float lrow[4];                 // per-lane partial row sums (reduced once at end)
  f32x4 zero4 = {0.f, 0.f, 0.f, 0.f};
  f32x4 oacc[4];
#pragma unroll
  for (int r = 0; r < 4; r++) lrow[r] = 0.f;
#pragma unroll
  for (int ni = 0; ni < 4; ni++) oacc[ni] = zero4;

  // staging: 16B-chunk XOR swizzle, same layout both buffers
  const int su0 = t * 8, su1 = t * 8 + 2048;
  const int srow0 = su0 >> 6, srow1 = su1 >> 6;
  const int scs0 = ((su0 >> 3) & 7) ^ (srow0 & 7);
  const int scs1 = ((su1 >> 3) & 7) ^ (srow1 & 7);

#define STAGE(J0, BUF) do {                                                       \
    gld_lds16(Kn + ((size_t)bh * SEQ + (J0) + srow0) * HD + scs0 * 8, &Ks[BUF][su0]); \
    gld_lds16(Vt + ((size_t)bh * HD + srow0) * SEQ + (J0) + scs0 * 8, &Vs[BUF][su0]); \
    gld_lds16(Kn + ((size_t)bh * SEQ + (J0) + srow1) * HD + scs1 * 8, &Ks[BUF][su1]); \
    gld_lds16(Vt + ((size_t)bh * HD + srow1) * SEQ + (J0) + scs1 * 8, &Vs[BUF][su1]); \
  } while (0)

  const int nj = (i0 >> 6) + 1;
  STAGE(0, 0);

  for (int jt = 0; jt < nj; jt++) {
    const int j0 = jt * 64;
    const int cur = jt & 1;
    __syncthreads();                       // buf[cur] ready; prev readers of buf[cur^1] done
    if (jt + 1 < nj) STAGE((jt + 1) * 64, cur ^ 1);   // prefetch overlaps compute below

    // S = Q K^T  (per wave: 16 rows x 64 cols)
    f32x4 s4[4];
#pragma unroll
    for (int ni = 0; ni < 4; ni++) {
      int rowj = ni * 16 + ln;
      bf16x8 kf0 = *reinterpret_cast<const bf16x8*>(&Ks[cur][rowj * 64 + ((0 * 4 + q) ^ (rowj & 7)) * 8]);
      bf16x8 kf1 = *reinterpret_cast<const bf16x8*>(&Ks[cur][rowj * 64 + ((1 * 4 + q) ^ (rowj & 7)) * 8]);
      f32x4 z = zero4;
      z = __builtin_amdgcn_mfma_f32_16x16x32_bf16(qf0, kf0, z, 0, 0, 0);
      z = __builtin_amdgcn_mfma_f32_16x16x32_bf16(qf1, kf1, z, 0, 0, 0);
      s4[ni] = z;
    }

    // causal mask (diagonal tile only)
    if (j0 == i0) {
#pragma unroll
      for (int ni = 0; ni < 4; ni++)
#pragma unroll
        for (int r = 0; r < 4; r++) {
          int irow = i0 + wave * 16 + q * 4 + r;
          int jcol = j0 + ni * 16 + ln;
          if (jcol > irow) s4[ni][r] = -3.0e38f;
        }
    }

    // fixed-max softmax: |s| <= 2 by Cauchy-Schwarz after per-head LN + scale.
    // p = exp(min(s,30)); per-lane partial row sums, no cross-lane work here.
#pragma unroll
    for (int ni = 0; ni < 4; ni++)
#pragma unroll
      for (int r = 0; r < 4; r++) {
        float p = __expf(fminf(s4[ni][r], 30.f));
        s4[ni][r] = p;
        lrow[r] += p;
      }

    // P: C-layout -> LDS -> A-layout (per-wave scratch, padded rows)
#pragma unroll
    for (int ni = 0; ni < 4; ni++)
#pragma unroll
      for (int r = 0; r < 4; r++)
        Ps[wave][(q * 4 + r) * 72 + ni * 16 + ln] = (bf16)s4[ni][r];
    asm volatile("s_waitcnt lgkmcnt(0)" ::: "memory");

    bf16x8 pf0 = *reinterpret_cast<const bf16x8*>(&Ps[wave][ln * 72 + q * 8]);
    bf16x8 pf1 = *reinterpret_cast<const bf16x8*>(&Ps[wave][ln * 72 + 32 + q * 8]);
#pragma unroll
    for (int ni = 0; ni < 4; ni++) {
      int rowd = ni * 16 + ln;
      bf16x8 vf0 = *reinterpret_cast<const bf16x8*>(&Vs[cur][rowd * 64 + ((0 * 4 + q) ^ (rowd & 7)) * 8]);
      bf16x8 vf1 = *reinterpret_cast<const bf16x8*>(&Vs[cur][rowd * 64 + ((1 * 4 + q) ^ (rowd & 7)) * 8]);
      oacc[ni] = __builtin_amdgcn_mfma_f32_16x16x32_bf16(pf0, vf0, oacc[ni], 0, 0, 0);
      oacc[ni] = __builtin_amdgcn_mfma_f32_16x16x32_bf16(pf1, vf1, oacc[ni], 0, 0, 0);
    }
  }
#undef STAGE

  // epilogue: one 16-lane reduction for l, normalize, store
  float inv[4];
#pragma unroll
  for (int r = 0; r < 4; r++) {
    float s = lrow[r];
#pragma unroll
    for (int mk = 1; mk < 16; mk <<= 1) s += __shfl_xor(s, mk, 64);
    inv[r] = 1.f / s;
  }
  int b = bh >> 4, h = bh & 15;
#pragma unroll
  for (int ni = 0; ni < 4; ni++)
#pragma unroll
    for (int r = 0; r < 4; r++) {
      int row = i0 + wave * 16 + q * 4 + r;
      O[(size_t)(b * SEQ + row) * EMB + h * HD + ni * 16 + ln] = (bf16)(oacc[ni][r] * inv[r]);
    }
}

// ---------------- launch ----------------
extern "C" void kernel_launch(void* const* d_in, const int* in_sizes, int n_in,
                              void* d_out, int out_size, void* d_ws, size_t ws_size,
                              hipStream_t stream)
{
  const float* x   = (const float*)d_in[0];
  const float* Wk  = (const float*)d_in[1];
  const float* Wq  = (const float*)d_in[2];
  const float* Wv  = (const float*)d_in[3];
  const float* Wo  = (const float*)d_in[4];
  const float* bo  = (const float*)d_in[5];
  const float* klg = (const float*)d_in[6];
  const float* klb = (const float*)d_in[7];
  const float* qlg = (const float*)d_in[8];
  const float* qlb = (const float*)d_in[9];
  float* out = (float*)d_out;

  char* ws = (char*)d_ws;
  const size_t OFF_XB  = 0;
  const size_t OFF_WB  = OFF_XB  + (size_t)BT * EMB * 2;
  const size_t OFF_KQV = OFF_WB  + (size_t)4 * EMB * EMB * 2;
  const size_t OFF_KN  = OFF_KQV + (size_t)BT * 3 * EMB * 2;
  const size_t OFF_QN  = OFF_KN  + (size_t)BT * EMB * 2;
  const size_t OFF_VT  = OFF_QN  + (size_t)BT * EMB * 2;
  const size_t OFF_END = OFF_VT  + (size_t)BT * EMB * 2;
  if (ws_size < OFF_END) return;

  bf16* xb   = (bf16*)(ws + OFF_XB);
  bf16* wb   = (bf16*)(ws + OFF_WB);
  bf16* kqv  = (bf16*)(ws + OFF_KQV);
  bf16* kn   = (bf16*)(ws + OFF_KN);
  bf16* qn   = (bf16*)(ws + OFF_QN);
  bf16* vt   = (bf16*)(ws + OFF_VT);
  bf16* ob   = (bf16*)(ws + OFF_KQV);    // alias: KQV dead after ln/v_trans

  cvt_f32_bf16<<<(BT * EMB / 4) / 256, 256, 0, stream>>>(x, xb, BT * EMB / 4);
  cvt_w4<<<(4 * EMB * EMB / 4) / 256, 256, 0, stream>>>(Wk, Wq, Wv, Wo, wb);

  gemm_bt<0><<<dim3(3 * EMB / 128, BT / 128), 256, 0, stream>>>(
      xb, wb, kqv, (float*)nullptr, (const float*)nullptr, BT, 3 * EMB, EMB);

  ln_head<<<BT * HEADS / 4, 256, 0, stream>>>(kqv + 0 * EMB, 3 * EMB, kn, klg, klb, QK_SCALE);
  ln_head<<<BT * HEADS / 4, 256, 0, stream>>>(kqv + 1 * EMB, 3 * EMB, qn, qlg, qlb, QK_SCALE);
  v_trans<<<dim3(SEQ / 64, BATCH * HEADS), 256, 0, stream>>>(kqv + 2 * EMB, 3 * EMB, vt);

  attn<<<dim3(SEQ / 64, BATCH * HEADS), 256, 0, stream>>>(qn, kn, vt, ob);

  gemm_bt<1><<<dim3(EMB / 128, BT / 128), 256, 0, stream>>>(
      ob, wb + (size_t)3 * EMB * EMB, (bf16*)nullptr, out, bo, BT, EMB, EMB);
}

// Round 4
// 368.967 us; speedup vs baseline: 1.1809x; 1.0055x over previous
//
#include <hip/hip_runtime.h>
#include <hip/hip_bf16.h>
#include <cstdint>

#define EMB 1024
#define HEADS 16
#define HD 64
#define BATCH 4
#define SEQ 2048
#define BT (BATCH*SEQ)                 // 8192 tokens
#define LNEPS 1e-5f
#define QK_SCALE 0.17677669529663687f  // 1024^-0.25
#define LOG2E 1.4426950408889634f

typedef __bf16 bf16;
typedef __bf16 bf16x8 __attribute__((ext_vector_type(8)));
typedef __bf16 bf16x4 __attribute__((ext_vector_type(4)));
typedef float  f32x4  __attribute__((ext_vector_type(4)));

typedef const __attribute__((address_space(1))) void* gas_ptr;
typedef __attribute__((address_space(3))) void*       las_ptr;

__device__ __forceinline__ void gld_lds16(const void* g, void* l) {
  __builtin_amdgcn_global_load_lds((gas_ptr)g, (las_ptr)l, 16, 0, 0);
}

// ---------------- fp32 -> bf16 conversion ----------------
__global__ void cvt_f32_bf16(const float* __restrict__ src, bf16* __restrict__ dst, int n4) {
  int i = blockIdx.x * blockDim.x + threadIdx.x;
  if (i >= n4) return;
  float4 f = reinterpret_cast<const float4*>(src)[i];
  bf16x4 o = { (bf16)f.x, (bf16)f.y, (bf16)f.z, (bf16)f.w };
  reinterpret_cast<bf16x4*>(dst)[i] = o;
}

// 4 weight matrices (1024x1024 each) -> contiguous bf16 [4*1024][1024]
__global__ void cvt_w4(const float* __restrict__ w0, const float* __restrict__ w1,
                       const float* __restrict__ w2, const float* __restrict__ w3,
                       bf16* __restrict__ dst) {
  int i = blockIdx.x * blockDim.x + threadIdx.x;   // over 4*262144 float4s
  int sel = i >> 18;
  int j = i & 262143;
  const float* s = (sel == 0) ? w0 : (sel == 1) ? w1 : (sel == 2) ? w2 : w3;
  float4 f = reinterpret_cast<const float4*>(s)[j];
  bf16x4 o = { (bf16)f.x, (bf16)f.y, (bf16)f.z, (bf16)f.w };
  reinterpret_cast<bf16x4*>(dst)[i] = o;
}

// ---------------- m97-style GEMM: C[M][N] = A[M][K] * B[N][K]^T ----------------
template<int OUTF32>
__global__ __launch_bounds__(256, 2) void gemm_bt(
    const bf16* __restrict__ A, const bf16* __restrict__ Bm,
    bf16* __restrict__ Cb, float* __restrict__ Cf, const float* __restrict__ bias,
    int M, int N, int K)
{
  __shared__ __align__(16) bf16 As[128 * 32];
  __shared__ __align__(16) bf16 Bs[128 * 32];

  const int t    = threadIdx.x;
  const int lane = t & 63;
  const int wave = t >> 6;
  const int q    = lane >> 4;
  const int ln   = lane & 15;
  const int m0   = blockIdx.y * 128;
  const int n0   = blockIdx.x * 128;
  const int wm   = (wave >> 1) * 64;
  const int wn   = (wave & 1) * 64;

  const int r0 = t >> 2;
  const int c0 = (t & 3) << 3;

  f32x4 zero4 = {0.f, 0.f, 0.f, 0.f};
  f32x4 acc[4][4];
#pragma unroll
  for (int i = 0; i < 4; i++)
#pragma unroll
    for (int j = 0; j < 4; j++) acc[i][j] = zero4;

  for (int k0 = 0; k0 < K; k0 += 32) {
    __syncthreads();
    const bf16* ga = A  + (size_t)(m0 + r0) * K + k0 + c0;
    const bf16* gb = Bm + (size_t)(n0 + r0) * K + k0 + c0;
    gld_lds16(ga,                  &As[t * 8]);
    gld_lds16(ga + (size_t)64 * K, &As[t * 8 + 2048]);
    gld_lds16(gb,                  &Bs[t * 8]);
    gld_lds16(gb + (size_t)64 * K, &Bs[t * 8 + 2048]);
    __syncthreads();

    bf16x8 af[4], bfr[4];
#pragma unroll
    for (int mi = 0; mi < 4; mi++)
      af[mi] = *reinterpret_cast<const bf16x8*>(&As[(wm + mi * 16 + ln) * 32 + q * 8]);
#pragma unroll
    for (int ni = 0; ni < 4; ni++)
      bfr[ni] = *reinterpret_cast<const bf16x8*>(&Bs[(wn + ni * 16 + ln) * 32 + q * 8]);
#pragma unroll
    for (int mi = 0; mi < 4; mi++)
#pragma unroll
      for (int ni = 0; ni < 4; ni++)
        acc[mi][ni] = __builtin_amdgcn_mfma_f32_16x16x32_bf16(af[mi], bfr[ni], acc[mi][ni], 0, 0, 0);
  }

#pragma unroll
  for (int mi = 0; mi < 4; mi++) {
#pragma unroll
    for (int ni = 0; ni < 4; ni++) {
#pragma unroll
      for (int r = 0; r < 4; r++) {
        int row = m0 + wm + mi * 16 + q * 4 + r;
        int col = n0 + wn + ni * 16 + ln;
        float v = acc[mi][ni][r];
        if (OUTF32) Cf[(size_t)row * N + col] = v + bias[col];
        else        Cb[(size_t)row * N + col] = (bf16)v;
      }
    }
  }
}

// ---------------- per-head LayerNorm for K and Q in one pass ----------------
// kqv: [8192][3072]; K at col 0, Q at col 1024. Outputs [bh][t][64].
// kscale includes log2(e) so attention can use exp2 directly.
__global__ void ln_kq(const bf16* __restrict__ kqv,
                      bf16* __restrict__ kn, bf16* __restrict__ qn,
                      const float* __restrict__ kg, const float* __restrict__ kb,
                      const float* __restrict__ qg, const float* __restrict__ qb,
                      float kscale, float qscale)
{
  int wave = threadIdx.x >> 6, lane = threadIdx.x & 63;
  int row = blockIdx.x * 4 + wave;        // row = t*16 + h
  int tok = row >> 4, h = row & 15;
  size_t base = (size_t)tok * (3 * EMB) + h * HD + lane;
  float xk = (float)kqv[base];
  float xq = (float)kqv[base + EMB];
  float sk = xk, sq = xq;
#pragma unroll
  for (int m = 1; m < 64; m <<= 1) { sk += __shfl_xor(sk, m, 64); sq += __shfl_xor(sq, m, 64); }
  float dk = xk - sk * (1.f / 64.f);
  float dq = xq - sq * (1.f / 64.f);
  float vk = dk * dk, vq = dq * dq;
#pragma unroll
  for (int m = 1; m < 64; m <<= 1) { vk += __shfl_xor(vk, m, 64); vq += __shfl_xor(vq, m, 64); }
  float yk = (dk * rsqrtf(vk * (1.f / 64.f) + LNEPS) * kg[lane] + kb[lane]) * kscale;
  float yq = (dq * rsqrtf(vq * (1.f / 64.f) + LNEPS) * qg[lane] + qb[lane]) * qscale;
  int b = tok >> 11;
  int tt = tok & 2047;
  size_t o = ((size_t)(b * HEADS + h) * SEQ + tt) * HD + lane;
  kn[o] = (bf16)yk;
  qn[o] = (bf16)yq;
}

// ---------------- V transpose: [t][3072] (V at col 2048) -> [bh][64 d][2048 t] ----------------
__global__ void v_trans(const bf16* __restrict__ in, int ldin, bf16* __restrict__ out)
{
  __shared__ __align__(16) bf16 tile[64][72];
  int bh = blockIdx.y, jt = blockIdx.x;
  int b = bh >> 4, h = bh & 15;
  int t = threadIdx.x;
#pragma unroll
  for (int p = 0; p < 2; p++) {
    int rowj = p * 32 + (t >> 3);
    int cold = (t & 7) << 3;
    bf16x8 v = *reinterpret_cast<const bf16x8*>(
        &in[(size_t)(b * SEQ + jt * 64 + rowj) * ldin + h * HD + cold]);
    *reinterpret_cast<bf16x8*>(&tile[rowj][cold]) = v;
  }
  __syncthreads();
#pragma unroll
  for (int p = 0; p < 2; p++) {
    int rowd = p * 32 + (t >> 3);
    int colj = (t & 7) << 3;
    bf16x8 v;
#pragma unroll
    for (int jj = 0; jj < 8; jj++) v[jj] = tile[colj + jj][rowd];
    *reinterpret_cast<bf16x8*>(&out[((size_t)bh * HD + rowd) * SEQ + jt * 64 + colj]) = v;
  }
}

// ---------------- flash attention (causal): 128-row Q blocks, 32 Q rows/wave ----------------
// Qn: [bh][t][64] (LN'd, * E^-.25). Kn: same but * E^-.25 * log2e. Vt: [bh][64][2048].
// Softmax is fixed-max exp2 (|s·log2e| <= 2.9 by Cauchy-Schwarz after per-head LN).
__global__ __launch_bounds__(256, 3) void attn(
    const bf16* __restrict__ Qn, const bf16* __restrict__ Kn, const bf16* __restrict__ Vt,
    bf16* __restrict__ O)
{
  __shared__ __align__(16) bf16 Ks[2][64 * 64];
  __shared__ __align__(16) bf16 Vs[2][64 * 64];
  __shared__ __align__(16) bf16 Ps[4][32 * 72];

  const int bh = blockIdx.y;
  const int i0 = (gridDim.x - 1 - (int)blockIdx.x) * 128;   // LPT: biggest first
  const int t = threadIdx.x, wave = t >> 6, lane = t & 63;
  const int q = lane >> 4, ln = lane & 15;
  const int qbase = i0 + wave * 32;

  // Q fragments: qf[mi][ks], rows qbase + mi*16 + ln, k = ks*32 + q*8 .. +8
  bf16x8 qf[2][2];
#pragma unroll
  for (int mi = 0; mi < 2; mi++) {
    const bf16* qp = Qn + ((size_t)bh * SEQ + qbase + mi * 16 + ln) * HD + q * 8;
    qf[mi][0] = *reinterpret_cast<const bf16x8*>(qp);
    qf[mi][1] = *reinterpret_cast<const bf16x8*>(qp + 32);
  }

  float lrow[8];
  f32x4 zero4 = {0.f, 0.f, 0.f, 0.f};
  f32x4 oacc[2][4];
#pragma unroll
  for (int i = 0; i < 8; i++) lrow[i] = 0.f;
#pragma unroll
  for (int mi = 0; mi < 2; mi++)
#pragma unroll
    for (int nd = 0; nd < 4; nd++) oacc[mi][nd] = zero4;

  // staging: 16B-chunk XOR swizzle (identical both buffers)
  const int su0 = t * 8, su1 = t * 8 + 2048;
  const int srow0 = su0 >> 6, srow1 = su1 >> 6;
  const int scs0 = ((su0 >> 3) & 7) ^ (srow0 & 7);
  const int scs1 = ((su1 >> 3) & 7) ^ (srow1 & 7);

#define STAGE(J0, BUF) do {                                                           \
    gld_lds16(Kn + ((size_t)bh * SEQ + (J0) + srow0) * HD + scs0 * 8, &Ks[BUF][su0]); \
    gld_lds16(Vt + ((size_t)bh * HD + srow0) * SEQ + (J0) + scs0 * 8, &Vs[BUF][su0]); \
    gld_lds16(Kn + ((size_t)bh * SEQ + (J0) + srow1) * HD + scs1 * 8, &Ks[BUF][su1]); \
    gld_lds16(Vt + ((size_t)bh * HD + srow1) * SEQ + (J0) + scs1 * 8, &Vs[BUF][su1]); \
  } while (0)

  const int nj = (i0 >> 6) + 2;
  STAGE(0, 0);

  for (int jt = 0; jt < nj; jt++) {
    const int j0 = jt * 64;
    const int cur = jt & 1;
    __syncthreads();                        // buf[cur] staged; old readers of buf[cur^1] done
    if (jt + 1 < nj) STAGE((jt + 1) * 64, cur ^ 1);

    if (j0 <= qbase + 31) {                 // wave has unmasked rows in this tile
      const bf16* KsC = Ks[cur];
      const bf16* VsC = Vs[cur];

      // S = Q K^T : 32 rows (2 mi) x 64 cols (4 ni), K = 64 (2 ks)
      f32x4 s4[2][4];
#pragma unroll
      for (int mi = 0; mi < 2; mi++)
#pragma unroll
        for (int ni = 0; ni < 4; ni++) s4[mi][ni] = zero4;
#pragma unroll
      for (int ks = 0; ks < 2; ks++) {
#pragma unroll
        for (int ni = 0; ni < 4; ni++) {
          int rowj = ni * 16 + ln;
          bf16x8 kf = *reinterpret_cast<const bf16x8*>(
              &KsC[rowj * 64 + (((ks * 4 + q) ^ (rowj & 7)) * 8)]);
#pragma unroll
          for (int mi = 0; mi < 2; mi++)
            s4[mi][ni] = __builtin_amdgcn_mfma_f32_16x16x32_bf16(qf[mi][ks], kf, s4[mi][ni], 0, 0, 0);
        }
      }

      // causal mask only on diagonal-overlapping tiles
      if (j0 + 63 > qbase) {
#pragma unroll
        for (int mi = 0; mi < 2; mi++)
#pragma unroll
          for (int ni = 0; ni < 4; ni++)
#pragma unroll
            for (int r = 0; r < 4; r++) {
              int irow = qbase + mi * 16 + q * 4 + r;
              int jcol = j0 + ni * 16 + ln;
              if (jcol > irow) s4[mi][ni][r] = -3.0e38f;
            }
      }

      // fixed-max softmax: p = 2^s (log2e folded into K scale); per-lane row partials
#pragma unroll
      for (int mi = 0; mi < 2; mi++)
#pragma unroll
        for (int ni = 0; ni < 4; ni++)
#pragma unroll
          for (int r = 0; r < 4; r++) {
            float p = exp2f(s4[mi][ni][r]);
            s4[mi][ni][r] = p;
            lrow[mi * 4 + r] += p;
          }

      // P: C-layout -> LDS -> A-layout (per-wave scratch, 72 stride)
#pragma unroll
      for (int mi = 0; mi < 2; mi++)
#pragma unroll
        for (int ni = 0; ni < 4; ni++)
#pragma unroll
          for (int r = 0; r < 4; r++)
            Ps[wave][(mi * 16 + q * 4 + r) * 72 + ni * 16 + ln] = (bf16)s4[mi][ni][r];
      asm volatile("s_waitcnt lgkmcnt(0)" ::: "memory");

      // O += P V : K-dim = 64 j (2 ks), N = 64 d (4 nd)
#pragma unroll
      for (int ks = 0; ks < 2; ks++) {
        bf16x8 pf[2];
#pragma unroll
        for (int mi = 0; mi < 2; mi++)
          pf[mi] = *reinterpret_cast<const bf16x8*>(&Ps[wave][(mi * 16 + ln) * 72 + ks * 32 + q * 8]);
#pragma unroll
        for (int nd = 0; nd < 4; nd++) {
          int rowd = nd * 16 + ln;
          bf16x8 vf = *reinterpret_cast<const bf16x8*>(
              &VsC[rowd * 64 + (((ks * 4 + q) ^ (rowd & 7)) * 8)]);
#pragma unroll
          for (int mi = 0; mi < 2; mi++)
            oacc[mi][nd] = __builtin_amdgcn_mfma_f32_16x16x32_bf16(pf[mi], vf, oacc[mi][nd], 0, 0, 0);
        }
      }
    }
  }
#undef STAGE

  // epilogue: reduce l across the 16 col-lanes, normalize, store
  float inv[8];
#pragma unroll
  for (int i = 0; i < 8; i++) {
    float s = lrow[i];
#pragma unroll
    for (int mk = 1; mk < 16; mk <<= 1) s += __shfl_xor(s, mk, 64);
    inv[i] = 1.f / s;
  }
  int b = bh >> 4, h = bh & 15;
#pragma unroll
  for (int mi = 0; mi < 2; mi++)
#pragma unroll
    for (int nd = 0; nd < 4; nd++)
#pragma unroll
      for (int r = 0; r < 4; r++) {
        int row = qbase + mi * 16 + q * 4 + r;
        O[(size_t)(b * SEQ + row) * EMB + h * HD + nd * 16 + ln] =
            (bf16)(oacc[mi][nd][r] * inv[mi * 4 + r]);
      }
}

// ---------------- launch ----------------
extern "C" void kernel_launch(void* const* d_in, const int* in_sizes, int n_in,
                              void* d_out, int out_size, void* d_ws, size_t ws_size,
                              hipStream_t stream)
{
  const float* x   = (const float*)d_in[0];
  const float* Wk  = (const float*)d_in[1];
  const float* Wq  = (const float*)d_in[2];
  const float* Wv  = (const float*)d_in[3];
  const float* Wo  = (const float*)d_in[4];
  const float* bo  = (const float*)d_in[5];
  const float* klg = (const float*)d_in[6];
  const float* klb = (const float*)d_in[7];
  const float* qlg = (const float*)d_in[8];
  const float* qlb = (const float*)d_in[9];
  float* out = (float*)d_out;

  char* ws = (char*)d_ws;
  const size_t OFF_XB  = 0;
  const size_t OFF_WB  = OFF_XB  + (size_t)BT * EMB * 2;
  const size_t OFF_KQV = OFF_WB  + (size_t)4 * EMB * EMB * 2;
  const size_t OFF_KN  = OFF_KQV + (size_t)BT * 3 * EMB * 2;
  const size_t OFF_QN  = OFF_KN  + (size_t)BT * EMB * 2;
  const size_t OFF_VT  = OFF_QN  + (size_t)BT * EMB * 2;
  const size_t OFF_END = OFF_VT  + (size_t)BT * EMB * 2;
  if (ws_size < OFF_END) return;

  bf16* xb   = (bf16*)(ws + OFF_XB);
  bf16* wb   = (bf16*)(ws + OFF_WB);
  bf16* kqv  = (bf16*)(ws + OFF_KQV);
  bf16* kn   = (bf16*)(ws + OFF_KN);
  bf16* qn   = (bf16*)(ws + OFF_QN);
  bf16* vt   = (bf16*)(ws + OFF_VT);
  bf16* ob   = (bf16*)(ws + OFF_KQV);    // alias: KQV dead after ln/v_trans

  cvt_f32_bf16<<<(BT * EMB / 4) / 256, 256, 0, stream>>>(x, xb, BT * EMB / 4);
  cvt_w4<<<(4 * EMB * EMB / 4) / 256, 256, 0, stream>>>(Wk, Wq, Wv, Wo, wb);

  gemm_bt<0><<<dim3(3 * EMB / 128, BT / 128), 256, 0, stream>>>(
      xb, wb, kqv, (float*)nullptr, (const float*)nullptr, BT, 3 * EMB, EMB);

  ln_kq<<<BT * HEADS / 4, 256, 0, stream>>>(kqv, kn, qn, klg, klb, qlg, qlb,
                                            QK_SCALE * LOG2E, QK_SCALE);
  v_trans<<<dim3(SEQ / 64, BATCH * HEADS), 256, 0, stream>>>(kqv + 2 * EMB, 3 * EMB, vt);

  attn<<<dim3(SEQ / 128, BATCH * HEADS), 256, 0, stream>>>(qn, kn, vt, ob);

  gemm_bt<1><<<dim3(EMB / 128, BT / 128), 256, 0, stream>>>(
      ob, wb + (size_t)3 * EMB * EMB, (bf16*)nullptr, out, bo, BT, EMB, EMB);
}